// Round 5
// baseline (181.181 us; speedup 1.0000x reference)
//
#include <hip/hip_runtime.h>

#define B_ 16
#define L_ 1024
#define M_ 1024
#define H_ 128

typedef unsigned short u16;
typedef unsigned int u32;
typedef __bf16 bf16x8 __attribute__((ext_vector_type(8)));
typedef float f32x4 __attribute__((ext_vector_type(4)));

__device__ __forceinline__ u16 f2bf(float x){
  u32 u = __float_as_uint(x);
  u = (u + 0x7fffu + ((u >> 16) & 1u)) >> 16;
  return (u16)u;
}

// ---------------------------------------------------------------------------
// zero rowsum|colsum|c_f32 accumulators (ws is poisoned 0xAA pre-launch)
// ---------------------------------------------------------------------------
__global__ __launch_bounds__(256) void zero_f32(float4* __restrict__ p, int n4)
{
  int i = blockIdx.x * 256 + threadIdx.x;
  int stride = gridDim.x * 256;
  for (; i < n4; i += stride) p[i] = make_float4(0.f, 0.f, 0.f, 0.f);
}

// ---------------------------------------------------------------------------
// prep2: one pass over text/modality f32. Per 64-row chunk:
//   - row-major bf16 (text scaled by tmw)        -> textw_bf / mod_bf
//   - mask-zeroed transposed bf16 [h][l]         -> textT_bf / modT_bf
//   - f32 dot with text_weight/modality_weight   -> t0 / s1m
// grid 512 = sel(2) x b(16) x chunk(16), 256 threads.
// ---------------------------------------------------------------------------
__global__ __launch_bounds__(256) void prep2(
    const float* __restrict__ text, const float* __restrict__ modality,
    const int* __restrict__ tmask, const int* __restrict__ mmask,
    const float* __restrict__ tw, const float* __restrict__ mw,
    const float* __restrict__ tmw,
    u16* __restrict__ textw_bf, u16* __restrict__ mod_bf,
    u16* __restrict__ textT_bf, u16* __restrict__ modT_bf,
    float* __restrict__ t0, float* __restrict__ s1m)
{
  int g = blockIdx.x;
  int sel = g >> 8;
  int b = (g >> 4) & 15;
  int r0 = (g & 15) * 64;
  const float* src = (sel ? modality : text) + ((size_t)b * 1024 + r0) * H_;
  const int* msk = (sel ? mmask : tmask) + b * 1024 + r0;
  const float* dotw = sel ? mw : tw;
  u16* rowout = (sel ? mod_bf : textw_bf) + ((size_t)b * 1024 + r0) * H_;
  u16* trout = (sel ? modT_bf : textT_bf) + (size_t)b * H_ * 1024 + r0;
  float* dotout = (sel ? s1m : t0) + b * 1024 + r0;

  __shared__ u16 tile[128][72];     // [h][l], 18.4 KB, rows 144B (16-aligned)
  int tid = threadIdx.x;
  int rgrp = tid >> 5;              // 0..7 (row group within pass)
  int lane32 = tid & 31;
  int h0 = lane32 * 4;
  float4 w4 = *(const float4*)&dotw[h0];
  float4 mv = sel ? make_float4(1.f, 1.f, 1.f, 1.f) : *(const float4*)&tmw[h0];
  float dpart[8];
  #pragma unroll
  for (int p = 0; p < 8; p++) {
    int row = rgrp + p * 8;
    float4 x = *(const float4*)&src[(size_t)row * H_ + h0];
    dpart[p] = x.x * w4.x + x.y * w4.y + x.z * w4.z + x.w * w4.w;
    uint2 pk;
    pk.x = (u32)f2bf(x.x * mv.x) | ((u32)f2bf(x.y * mv.y) << 16);
    pk.y = (u32)f2bf(x.z * mv.z) | ((u32)f2bf(x.w * mv.w) << 16);
    *(uint2*)&rowout[(size_t)row * H_ + h0] = pk;
    int mk = msk[row];
    tile[h0 + 0][row] = mk ? f2bf(x.x) : (u16)0;
    tile[h0 + 1][row] = mk ? f2bf(x.y) : (u16)0;
    tile[h0 + 2][row] = mk ? f2bf(x.z) : (u16)0;
    tile[h0 + 3][row] = mk ? f2bf(x.w) : (u16)0;
  }
  #pragma unroll
  for (int p = 0; p < 8; p++) {
    float d = dpart[p];
    #pragma unroll
    for (int off = 1; off < 32; off <<= 1) d += __shfl_xor(d, off);
    if (lane32 == 0) dotout[rgrp + p * 8] = d;
  }
  __syncthreads();
  int lcol = (tid & 7) * 8;
  #pragma unroll
  for (int p = 0; p < 4; p++) {
    int h = (tid >> 3) + p * 32;
    uint4 v = *(const uint4*)&tile[h][lcol];
    *(uint4*)&trout[(size_t)h * 1024 + lcol] = v;
  }
}

// ---------------------------------------------------------------------------
// gemm_exp: s = textw @ mod^T + t0 + s1m + bias; E = exp(s) (no max-sub:
// |s| <~ 15). Writes E^T (M,L) bf16 via LDS repack; atomics for masked
// rowsum/colsum. Tile 64(l) x 128(m), 4 waves. 1D grid 2048, XCD swizzle.
// ---------------------------------------------------------------------------
__global__ __launch_bounds__(256) void gemm_exp(
    const u16* __restrict__ A, const u16* __restrict__ Bm,
    const float* __restrict__ t0, const float* __restrict__ s1m,
    const float* __restrict__ bias, const int* __restrict__ tmask,
    const int* __restrict__ mmask, float* __restrict__ rowsum,
    float* __restrict__ colsum, u16* __restrict__ ET)
{
  int f = blockIdx.x;                       // 2048 = 8 xcd * 256
  int orig = (f & 7) * 256 + (f >> 3);      // each XCD: 2 batches
  int b = orig >> 7;
  int a0 = (orig & 15) * 64, b0 = ((orig >> 4) & 7) * 128;
  int tid = threadIdx.x, lane = tid & 63, wid = tid >> 6;
  int wr = wid >> 1, wc = wid & 1;
  int c = lane & 15, q = lane >> 4;
  __shared__ __align__(16) char smem[24576];
  const u16* Ab = A + (size_t)(b * L_ + a0) * H_;
  const u16* Bb = Bm + (size_t)(b * M_ + b0) * H_;
  f32x4 acc[2][4];
  #pragma unroll
  for (int i = 0; i < 2; i++)
    #pragma unroll
    for (int j = 0; j < 4; j++) acc[i][j] = (f32x4){0.f, 0.f, 0.f, 0.f};
  for (int kt = 0; kt < 2; kt++) {
    __syncthreads();
    #pragma unroll
    for (int i = 0; i < 2; i++) {      // stage A: 64x64
      int cc = tid + 256 * i;
      int row = cc >> 3, col8 = cc & 7;
      uint4 v = *(const uint4*)(Ab + (size_t)row * H_ + kt * 64 + col8 * 8);
      *(uint4*)(smem + row * 128 + ((col8 * 16) ^ ((row & 7) << 4))) = v;
    }
    #pragma unroll
    for (int i = 0; i < 4; i++) {      // stage B: 128x64
      int cc = tid + 256 * i;
      int row = cc >> 3, col8 = cc & 7;
      uint4 v = *(const uint4*)(Bb + (size_t)row * H_ + kt * 64 + col8 * 8);
      *(uint4*)(smem + 8192 + row * 128 + ((col8 * 16) ^ ((row & 7) << 4))) = v;
    }
    __syncthreads();
    #pragma unroll
    for (int kk = 0; kk < 2; kk++) {
      int kbyte = kk * 64 + (q << 4);
      bf16x8 af[2], bfr[4];
      #pragma unroll
      for (int i = 0; i < 2; i++) {
        int ra = wr * 32 + i * 16 + c;
        af[i] = *(const bf16x8*)(smem + ra * 128 + (kbyte ^ ((ra & 7) << 4)));
      }
      #pragma unroll
      for (int j = 0; j < 4; j++) {
        int rb = wc * 64 + j * 16 + c;
        bfr[j] = *(const bf16x8*)(smem + 8192 + rb * 128 + (kbyte ^ ((rb & 7) << 4)));
      }
      #pragma unroll
      for (int i = 0; i < 2; i++)
        #pragma unroll
        for (int j = 0; j < 4; j++)
          acc[i][j] = __builtin_amdgcn_mfma_f32_16x16x32_bf16(af[i], bfr[j], acc[i][j], 0, 0, 0);
    }
  }
  float biasv = bias[0];
  float t0v[2][4];
  int tmv[2][4];
  #pragma unroll
  for (int i = 0; i < 2; i++)
    #pragma unroll
    for (int r = 0; r < 4; r++) {
      int ar = a0 + wr * 32 + i * 16 + q * 4 + r;
      t0v[i][r] = t0[b * L_ + ar];
      tmv[i][r] = tmask[b * L_ + ar];
    }
  float s1v[4];
  int mmv[4];
  #pragma unroll
  for (int j = 0; j < 4; j++) {
    int gcol = b0 + wc * 64 + j * 16 + c;
    s1v[j] = s1m[b * M_ + gcol];
    mmv[j] = mmask[b * M_ + gcol];
  }
  float ev[2][4][4];
  #pragma unroll
  for (int i = 0; i < 2; i++)
    #pragma unroll
    for (int j = 0; j < 4; j++)
      #pragma unroll
      for (int r = 0; r < 4; r++)
        ev[i][j][r] = __expf(acc[i][j][r] + t0v[i][r] + s1v[j] + biasv);
  #pragma unroll
  for (int i = 0; i < 2; i++)
    #pragma unroll
    for (int r = 0; r < 4; r++) {
      float prs = 0.f;
      #pragma unroll
      for (int j = 0; j < 4; j++) prs += mmv[j] ? ev[i][j][r] : 0.f;
      #pragma unroll
      for (int off = 1; off < 16; off <<= 1) prs += __shfl_xor(prs, off);
      if (c == 0) {
        int ar = a0 + wr * 32 + i * 16 + q * 4 + r;
        atomicAdd(&rowsum[b * L_ + ar], prs);
      }
    }
  #pragma unroll
  for (int j = 0; j < 4; j++) {
    float pcs = 0.f;
    #pragma unroll
    for (int i = 0; i < 2; i++)
      #pragma unroll
      for (int r = 0; r < 4; r++) pcs += tmv[i][r] ? ev[i][j][r] : 0.f;
    pcs += __shfl_xor(pcs, 16);
    pcs += __shfl_xor(pcs, 32);
    if (q == 0) {
      int gcol = b0 + wc * 64 + j * 16 + c;
      atomicAdd(&colsum[b * M_ + gcol], pcs);
    }
  }
  __syncthreads();
  u16* et = (u16*)smem;
  #pragma unroll
  for (int i = 0; i < 2; i++)
    #pragma unroll
    for (int j = 0; j < 4; j++) {
      int gcolL = wc * 64 + j * 16 + c;
      int arL = wr * 32 + i * 16 + q * 4;
      u32 lo = (u32)f2bf(ev[i][j][0]) | ((u32)f2bf(ev[i][j][1]) << 16);
      u32 hi = (u32)f2bf(ev[i][j][2]) | ((u32)f2bf(ev[i][j][3]) << 16);
      uint2 pk; pk.x = lo; pk.y = hi;
      *(uint2*)&et[gcolL * 72 + arL] = pk;
    }
  __syncthreads();
  #pragma unroll
  for (int it = 0; it < 4; it++) {
    int mrow = (tid >> 3) + it * 32;
    int l8 = tid & 7;
    uint4 v = *(const uint4*)&et[mrow * 72 + l8 * 8];
    *(uint4*)&ET[((size_t)(b * M_ + b0 + mrow)) * L_ + a0 + l8 * 8] = v;
  }
}

// ---------------------------------------------------------------------------
// gemm_ct: c_f32[h][m] += sum_l textT_m[h][l] * ET[m][l]  (split-K x2, f32
// atomics). 512 threads, 8 waves (2x4), tile 64x128. 1D grid 512, XCD swizzle.
// ---------------------------------------------------------------------------
__global__ __launch_bounds__(512) void gemm_ct(
    const u16* __restrict__ A, const u16* __restrict__ ET,
    float* __restrict__ c_f32)
{
  int f = blockIdx.x;                      // 512 = 8 * 64
  int orig = (f & 7) * 64 + (f >> 3);      // each XCD: 2 batches
  int b = orig >> 5;
  int x = orig & 3, y = (orig >> 2) & 7;
  int ia = x & 1, ks = x >> 1;
  int a0 = ia * 64, b0 = y * 128;
  int tid = threadIdx.x, lane = tid & 63, wid = tid >> 6;
  int wr = wid >> 2, wc = wid & 3;
  int c = lane & 15, q = lane >> 4;
  __shared__ __align__(16) char smem[24576];
  const u16* Ab = A + (size_t)(b * H_ + a0) * L_;
  const u16* Bb = ET + (size_t)(b * M_ + b0) * L_;
  f32x4 acc[2][2];
  #pragma unroll
  for (int i = 0; i < 2; i++)
    #pragma unroll
    for (int j = 0; j < 2; j++) acc[i][j] = (f32x4){0.f, 0.f, 0.f, 0.f};
  for (int kt = ks * 8; kt < ks * 8 + 8; kt++) {
    __syncthreads();
    {
      int row = tid >> 3, col8 = tid & 7;
      uint4 v = *(const uint4*)(Ab + (size_t)row * L_ + kt * 64 + col8 * 8);
      *(uint4*)(smem + row * 128 + ((col8 * 16) ^ ((row & 7) << 4))) = v;
    }
    #pragma unroll
    for (int i = 0; i < 2; i++) {
      int cc = tid + 512 * i;
      int row = cc >> 3, col8 = cc & 7;
      uint4 v = *(const uint4*)(Bb + (size_t)row * L_ + kt * 64 + col8 * 8);
      *(uint4*)(smem + 8192 + row * 128 + ((col8 * 16) ^ ((row & 7) << 4))) = v;
    }
    __syncthreads();
    #pragma unroll
    for (int kk = 0; kk < 2; kk++) {
      int kbyte = kk * 64 + (q << 4);
      bf16x8 af[2], bfr[2];
      #pragma unroll
      for (int i = 0; i < 2; i++) {
        int ra = wr * 32 + i * 16 + c;
        af[i] = *(const bf16x8*)(smem + ra * 128 + (kbyte ^ ((ra & 7) << 4)));
      }
      #pragma unroll
      for (int j = 0; j < 2; j++) {
        int rb = wc * 32 + j * 16 + c;
        bfr[j] = *(const bf16x8*)(smem + 8192 + rb * 128 + (kbyte ^ ((rb & 7) << 4)));
      }
      #pragma unroll
      for (int i = 0; i < 2; i++)
        #pragma unroll
        for (int j = 0; j < 2; j++)
          acc[i][j] = __builtin_amdgcn_mfma_f32_16x16x32_bf16(af[i], bfr[j], acc[i][j], 0, 0, 0);
    }
  }
  #pragma unroll
  for (int i = 0; i < 2; i++)
    #pragma unroll
    for (int j = 0; j < 2; j++) {
      int arow0 = a0 + wr * 32 + i * 16 + q * 4;
      int gcol = b0 + wc * 32 + j * 16 + c;
      #pragma unroll
      for (int r = 0; r < 4; r++)
        atomicAdd(&c_f32[((size_t)(b * H_ + arow0 + r)) * M_ + gcol], acc[i][j][r]);
    }
}

// ---------------------------------------------------------------------------
// gemm_ab: a = (E @ mod_mT^T)/rowsum, bb = (E @ cT^T)/rowsum, K = M.
// B2 staged directly from c_f32 scaled by invcm = mmask/colsum (norm_ct
// folded in). 512 threads, 8 waves (2x4), tile 64(l) x 128(h).
// Writes out[text | a | text*a | text*bb]. 1D grid 256, XCD swizzle.
// ---------------------------------------------------------------------------
__global__ __launch_bounds__(512) void gemm_ab(
    const u16* __restrict__ ET, const u16* __restrict__ B1,
    const float* __restrict__ c_f32, const float* __restrict__ colsum,
    const int* __restrict__ mmask, const float* __restrict__ rowsum,
    const float* __restrict__ text, float* __restrict__ out)
{
  int f = blockIdx.x;                      // 256 = 8 * 32
  int orig = (f & 7) * 32 + (f >> 3);      // each XCD: 2 batches
  int b = orig >> 4;
  int a0 = (orig & 15) * 64;
  int tid = threadIdx.x, lane = tid & 63, wid = tid >> 6;
  int wr = wid >> 2, wc = wid & 3;
  int c = lane & 15, q = lane >> 4;
  __shared__ __align__(16) u16 At[64 * 76];       // [m 64][l 64] pad 76
  __shared__ __align__(16) char Bs[2][16384];
  __shared__ float invcm[1024];
  const u16* ETb = ET + (size_t)b * M_ * L_;
  const u16* B1b = B1 + (size_t)b * H_ * M_;
  const float* cfb = c_f32 + (size_t)b * H_ * M_;
  for (int i = tid; i < 1024; i += 512)
    invcm[i] = mmask[b * M_ + i] ? 1.0f / fmaxf(colsum[b * M_ + i], 1e-30f) : 0.f;
  f32x4 acc_a[2][2], acc_b[2][2];
  #pragma unroll
  for (int i = 0; i < 2; i++)
    #pragma unroll
    for (int j = 0; j < 2; j++) {
      acc_a[i][j] = (f32x4){0.f, 0.f, 0.f, 0.f};
      acc_b[i][j] = (f32x4){0.f, 0.f, 0.f, 0.f};
    }
  for (int kt = 0; kt < 16; kt++) {
    __syncthreads();
    {   // stage A (64 l x 64 m) from E^T rows [kt*64,+64), cols [a0,+64)
      int mloc = tid >> 3, l8 = tid & 7;
      uint4 v = *(const uint4*)&ETb[((size_t)(kt * 64 + mloc)) * L_ + a0 + l8 * 8];
      u16* rp = At + mloc * 76 + l8 * 8;
      uint2 p0; p0.x = v.x; p0.y = v.y;
      uint2 p1; p1.x = v.z; p1.y = v.w;
      *(uint2*)rp = p0;
      *(uint2*)(rp + 4) = p1;
    }
    #pragma unroll
    for (int i = 0; i < 2; i++) {       // stage B1 (bf16) + B2 (from c_f32)
      int cc = tid + 512 * i;
      int row = cc >> 3, col8 = cc & 7;
      uint4 v1 = *(const uint4*)(B1b + (size_t)row * M_ + kt * 64 + col8 * 8);
      *(uint4*)(Bs[0] + row * 128 + ((col8 * 16) ^ ((row & 7) << 4))) = v1;
      int mbase = kt * 64 + col8 * 8;
      float4 xa = *(const float4*)&cfb[(size_t)row * M_ + mbase];
      float4 xb = *(const float4*)&cfb[(size_t)row * M_ + mbase + 4];
      float4 ia4 = *(const float4*)&invcm[mbase];
      float4 ib4 = *(const float4*)&invcm[mbase + 4];
      uint4 v2;
      v2.x = (u32)f2bf(xa.x * ia4.x) | ((u32)f2bf(xa.y * ia4.y) << 16);
      v2.y = (u32)f2bf(xa.z * ia4.z) | ((u32)f2bf(xa.w * ia4.w) << 16);
      v2.z = (u32)f2bf(xb.x * ib4.x) | ((u32)f2bf(xb.y * ib4.y) << 16);
      v2.w = (u32)f2bf(xb.z * ib4.z) | ((u32)f2bf(xb.w * ib4.w) << 16);
      *(uint4*)(Bs[1] + row * 128 + ((col8 * 16) ^ ((row & 7) << 4))) = v2;
    }
    __syncthreads();
    #pragma unroll
    for (int kk = 0; kk < 2; kk++) {
      int kbyte = kk * 64 + (q << 4);
      bf16x8 af[2], b1f[2], b2f[2];
      #pragma unroll
      for (int i = 0; i < 2; i++) {
        int lidx = wr * 32 + i * 16 + c;
        int mbase = kk * 32 + q * 8;
        union { unsigned short s[8]; bf16x8 v; } ua;
        #pragma unroll
        for (int e = 0; e < 8; e++) ua.s[e] = At[(mbase + e) * 76 + lidx];
        af[i] = ua.v;
      }
      #pragma unroll
      for (int j = 0; j < 2; j++) {
        int rb = wc * 32 + j * 16 + c;
        b1f[j] = *(const bf16x8*)(Bs[0] + rb * 128 + (kbyte ^ ((rb & 7) << 4)));
        b2f[j] = *(const bf16x8*)(Bs[1] + rb * 128 + (kbyte ^ ((rb & 7) << 4)));
      }
      #pragma unroll
      for (int i = 0; i < 2; i++)
        #pragma unroll
        for (int j = 0; j < 2; j++) {
          acc_a[i][j] = __builtin_amdgcn_mfma_f32_16x16x32_bf16(af[i], b1f[j], acc_a[i][j], 0, 0, 0);
          acc_b[i][j] = __builtin_amdgcn_mfma_f32_16x16x32_bf16(af[i], b2f[j], acc_b[i][j], 0, 0, 0);
        }
    }
  }
  float irs[2][4];
  #pragma unroll
  for (int i = 0; i < 2; i++)
    #pragma unroll
    for (int r = 0; r < 4; r++) {
      int ar = a0 + wr * 32 + i * 16 + q * 4 + r;
      irs[i][r] = 1.0f / fmaxf(rowsum[b * L_ + ar], 1e-30f);
    }
  #pragma unroll
  for (int i = 0; i < 2; i++)
    #pragma unroll
    for (int j = 0; j < 2; j++) {
      int gcol = wc * 32 + j * 16 + c;
      #pragma unroll
      for (int r = 0; r < 4; r++) {
        int ar = a0 + wr * 32 + i * 16 + q * 4 + r;
        float av = acc_a[i][j][r] * irs[i][r];
        float bv = acc_b[i][j][r] * irs[i][r];
        float tv = text[((size_t)(b * L_ + ar)) * H_ + gcol];
        size_t base = ((size_t)(b * L_ + ar)) * 512 + gcol;
        out[base] = tv;
        out[base + 128] = av;
        out[base + 256] = tv * av;
        out[base + 384] = tv * bv;
      }
    }
}

// ---------------------------------------------------------------------------
extern "C" void kernel_launch(void* const* d_in, const int* in_sizes, int n_in,
                              void* d_out, int out_size, void* d_ws, size_t ws_size,
                              hipStream_t stream) {
  const float* text = (const float*)d_in[0];
  const float* modality = (const float*)d_in[1];
  const int* text_mask = (const int*)d_in[2];
  const int* modality_mask = (const int*)d_in[3];
  const float* text_weight = (const float*)d_in[4];
  const float* modality_weight = (const float*)d_in[5];
  const float* tmw = (const float*)d_in[6];
  const float* bias = (const float*)d_in[7];
  float* out = (float*)d_out;
  (void)in_sizes; (void)n_in; (void)out_size; (void)ws_size;

  char* ws = (char*)d_ws;
  size_t off = 0;
  auto alloc = [&](size_t bytes) { void* p = ws + off; off += (bytes + 255) & ~(size_t)255; return p; };
  u16*   ET       = (u16*)  alloc((size_t)B_ * M_ * L_ * 2);   // 33.5MB
  u16*   textw_bf = (u16*)  alloc((size_t)B_ * L_ * H_ * 2);
  u16*   mod_bf   = (u16*)  alloc((size_t)B_ * M_ * H_ * 2);
  u16*   textT_bf = (u16*)  alloc((size_t)B_ * H_ * L_ * 2);   // masked by tmask
  u16*   mod_bfT  = (u16*)  alloc((size_t)B_ * H_ * M_ * 2);   // masked by mmask
  float* t0       = (float*)alloc((size_t)B_ * L_ * 4);
  float* s1m      = (float*)alloc((size_t)B_ * M_ * 4);
  // contiguous zero region: rowsum | colsum | c_f32
  float* rowsum   = (float*)alloc((size_t)B_ * L_ * 4);
  float* colsum   = (float*)alloc((size_t)B_ * M_ * 4);
  float* c_f32    = (float*)alloc((size_t)B_ * H_ * M_ * 4);   // 8.4MB

  int n4 = (B_ * (L_ + M_) + B_ * H_ * M_) / 4;
  zero_f32<<<2048, 256, 0, stream>>>((float4*)rowsum, n4);
  prep2<<<512, 256, 0, stream>>>(text, modality, text_mask, modality_mask,
      text_weight, modality_weight, tmw,
      textw_bf, mod_bf, textT_bf, mod_bfT, t0, s1m);
  gemm_exp<<<2048, 256, 0, stream>>>(textw_bf, mod_bf, t0, s1m, bias,
      text_mask, modality_mask, rowsum, colsum, ET);
  gemm_ct<<<512, 512, 0, stream>>>(textT_bf, ET, c_f32);
  gemm_ab<<<256, 512, 0, stream>>>(ET, mod_bfT, c_f32, colsum, modality_mask,
      rowsum, text, out);
}

// Round 6
// 166.016 us; speedup vs baseline: 1.0913x; 1.0913x over previous
//
#include <hip/hip_runtime.h>

#define B_ 16
#define L_ 1024
#define M_ 1024
#define H_ 128

typedef unsigned short u16;
typedef unsigned int u32;
typedef __bf16 bf16x8 __attribute__((ext_vector_type(8)));
typedef float f32x4 __attribute__((ext_vector_type(4)));

__device__ __forceinline__ u16 f2bf(float x){
  u32 u = __float_as_uint(x);
  u = (u + 0x7fffu + ((u >> 16) & 1u)) >> 16;
  return (u16)u;
}

// ---------------------------------------------------------------------------
// zero rowsum|colsum|c_f32 accumulators (ws is poisoned 0xAA pre-launch)
// ---------------------------------------------------------------------------
__global__ __launch_bounds__(256) void zero_f32(float4* __restrict__ p, int n4)
{
  int i = blockIdx.x * 256 + threadIdx.x;
  int stride = gridDim.x * 256;
  for (; i < n4; i += stride) p[i] = make_float4(0.f, 0.f, 0.f, 0.f);
}

// ---------------------------------------------------------------------------
// prep2: one pass over text/modality f32. Per 64-row chunk:
//   - row-major bf16 (text scaled by tmw)        -> textw_bf / mod_bf
//   - mask-zeroed transposed bf16 [h][l]         -> textT_bf / modT_bf
//   - f32 dot with text_weight/modality_weight   -> t0 / s1m
// grid 512 = sel(2) x b(16) x chunk(16), 256 threads.
// ---------------------------------------------------------------------------
__global__ __launch_bounds__(256) void prep2(
    const float* __restrict__ text, const float* __restrict__ modality,
    const int* __restrict__ tmask, const int* __restrict__ mmask,
    const float* __restrict__ tw, const float* __restrict__ mw,
    const float* __restrict__ tmw,
    u16* __restrict__ textw_bf, u16* __restrict__ mod_bf,
    u16* __restrict__ textT_bf, u16* __restrict__ modT_bf,
    float* __restrict__ t0, float* __restrict__ s1m)
{
  int g = blockIdx.x;
  int sel = g >> 8;
  int b = (g >> 4) & 15;
  int r0 = (g & 15) * 64;
  const float* src = (sel ? modality : text) + ((size_t)b * 1024 + r0) * H_;
  const int* msk = (sel ? mmask : tmask) + b * 1024 + r0;
  const float* dotw = sel ? mw : tw;
  u16* rowout = (sel ? mod_bf : textw_bf) + ((size_t)b * 1024 + r0) * H_;
  u16* trout = (sel ? modT_bf : textT_bf) + (size_t)b * H_ * 1024 + r0;
  float* dotout = (sel ? s1m : t0) + b * 1024 + r0;

  __shared__ u16 tile[128][72];     // [h][l], 18.4 KB, rows 144B (16-aligned)
  int tid = threadIdx.x;
  int rgrp = tid >> 5;              // 0..7 (row group within pass)
  int lane32 = tid & 31;
  int h0 = lane32 * 4;
  float4 w4 = *(const float4*)&dotw[h0];
  float4 mv = sel ? make_float4(1.f, 1.f, 1.f, 1.f) : *(const float4*)&tmw[h0];
  float dpart[8];
  #pragma unroll
  for (int p = 0; p < 8; p++) {
    int row = rgrp + p * 8;
    float4 x = *(const float4*)&src[(size_t)row * H_ + h0];
    dpart[p] = x.x * w4.x + x.y * w4.y + x.z * w4.z + x.w * w4.w;
    uint2 pk;
    pk.x = (u32)f2bf(x.x * mv.x) | ((u32)f2bf(x.y * mv.y) << 16);
    pk.y = (u32)f2bf(x.z * mv.z) | ((u32)f2bf(x.w * mv.w) << 16);
    *(uint2*)&rowout[(size_t)row * H_ + h0] = pk;
    int mk = msk[row];
    tile[h0 + 0][row] = mk ? f2bf(x.x) : (u16)0;
    tile[h0 + 1][row] = mk ? f2bf(x.y) : (u16)0;
    tile[h0 + 2][row] = mk ? f2bf(x.z) : (u16)0;
    tile[h0 + 3][row] = mk ? f2bf(x.w) : (u16)0;
  }
  #pragma unroll
  for (int p = 0; p < 8; p++) {
    float d = dpart[p];
    #pragma unroll
    for (int off = 1; off < 32; off <<= 1) d += __shfl_xor(d, off);
    if (lane32 == 0) dotout[rgrp + p * 8] = d;
  }
  __syncthreads();
  int lcol = (tid & 7) * 8;
  #pragma unroll
  for (int p = 0; p < 4; p++) {
    int h = (tid >> 3) + p * 32;
    uint4 v = *(const uint4*)&tile[h][lcol];
    *(uint4*)&trout[(size_t)h * 1024 + lcol] = v;
  }
}

// ---------------------------------------------------------------------------
// gemm_exp: s = textw @ mod^T + t0 + s1m + bias; E = exp(s) (no max-sub:
// |s| <~ 15). Writes E^T (M,L) bf16 via LDS repack; atomics for masked
// rowsum/colsum. Tile 64(l) x 128(m), 4 waves. 1D grid 2048, XCD swizzle.
// ---------------------------------------------------------------------------
__global__ __launch_bounds__(256) void gemm_exp(
    const u16* __restrict__ A, const u16* __restrict__ Bm,
    const float* __restrict__ t0, const float* __restrict__ s1m,
    const float* __restrict__ bias, const int* __restrict__ tmask,
    const int* __restrict__ mmask, float* __restrict__ rowsum,
    float* __restrict__ colsum, u16* __restrict__ ET)
{
  int f = blockIdx.x;                       // 2048 = 8 xcd * 256
  int orig = (f & 7) * 256 + (f >> 3);      // each XCD: 2 batches
  int b = orig >> 7;
  int a0 = (orig & 15) * 64, b0 = ((orig >> 4) & 7) * 128;
  int tid = threadIdx.x, lane = tid & 63, wid = tid >> 6;
  int wr = wid >> 1, wc = wid & 1;
  int c = lane & 15, q = lane >> 4;
  __shared__ __align__(16) char smem[24576];
  const u16* Ab = A + (size_t)(b * L_ + a0) * H_;
  const u16* Bb = Bm + (size_t)(b * M_ + b0) * H_;
  f32x4 acc[2][4];
  #pragma unroll
  for (int i = 0; i < 2; i++)
    #pragma unroll
    for (int j = 0; j < 4; j++) acc[i][j] = (f32x4){0.f, 0.f, 0.f, 0.f};
  for (int kt = 0; kt < 2; kt++) {
    __syncthreads();
    #pragma unroll
    for (int i = 0; i < 2; i++) {      // stage A: 64x64
      int cc = tid + 256 * i;
      int row = cc >> 3, col8 = cc & 7;
      uint4 v = *(const uint4*)(Ab + (size_t)row * H_ + kt * 64 + col8 * 8);
      *(uint4*)(smem + row * 128 + ((col8 * 16) ^ ((row & 7) << 4))) = v;
    }
    #pragma unroll
    for (int i = 0; i < 4; i++) {      // stage B: 128x64
      int cc = tid + 256 * i;
      int row = cc >> 3, col8 = cc & 7;
      uint4 v = *(const uint4*)(Bb + (size_t)row * H_ + kt * 64 + col8 * 8);
      *(uint4*)(smem + 8192 + row * 128 + ((col8 * 16) ^ ((row & 7) << 4))) = v;
    }
    __syncthreads();
    #pragma unroll
    for (int kk = 0; kk < 2; kk++) {
      int kbyte = kk * 64 + (q << 4);
      bf16x8 af[2], bfr[4];
      #pragma unroll
      for (int i = 0; i < 2; i++) {
        int ra = wr * 32 + i * 16 + c;
        af[i] = *(const bf16x8*)(smem + ra * 128 + (kbyte ^ ((ra & 7) << 4)));
      }
      #pragma unroll
      for (int j = 0; j < 4; j++) {
        int rb = wc * 64 + j * 16 + c;
        bfr[j] = *(const bf16x8*)(smem + 8192 + rb * 128 + (kbyte ^ ((rb & 7) << 4)));
      }
      #pragma unroll
      for (int i = 0; i < 2; i++)
        #pragma unroll
        for (int j = 0; j < 4; j++)
          acc[i][j] = __builtin_amdgcn_mfma_f32_16x16x32_bf16(af[i], bfr[j], acc[i][j], 0, 0, 0);
    }
  }
  float biasv = bias[0];
  float t0v[2][4];
  int tmv[2][4];
  #pragma unroll
  for (int i = 0; i < 2; i++)
    #pragma unroll
    for (int r = 0; r < 4; r++) {
      int ar = a0 + wr * 32 + i * 16 + q * 4 + r;
      t0v[i][r] = t0[b * L_ + ar];
      tmv[i][r] = tmask[b * L_ + ar];
    }
  float s1v[4];
  int mmv[4];
  #pragma unroll
  for (int j = 0; j < 4; j++) {
    int gcol = b0 + wc * 64 + j * 16 + c;
    s1v[j] = s1m[b * M_ + gcol];
    mmv[j] = mmask[b * M_ + gcol];
  }
  float ev[2][4][4];
  #pragma unroll
  for (int i = 0; i < 2; i++)
    #pragma unroll
    for (int j = 0; j < 4; j++)
      #pragma unroll
      for (int r = 0; r < 4; r++)
        ev[i][j][r] = __expf(acc[i][j][r] + t0v[i][r] + s1v[j] + biasv);
  #pragma unroll
  for (int i = 0; i < 2; i++)
    #pragma unroll
    for (int r = 0; r < 4; r++) {
      float prs = 0.f;
      #pragma unroll
      for (int j = 0; j < 4; j++) prs += mmv[j] ? ev[i][j][r] : 0.f;
      #pragma unroll
      for (int off = 1; off < 16; off <<= 1) prs += __shfl_xor(prs, off);
      if (c == 0) {
        int ar = a0 + wr * 32 + i * 16 + q * 4 + r;
        atomicAdd(&rowsum[b * L_ + ar], prs);
      }
    }
  #pragma unroll
  for (int j = 0; j < 4; j++) {
    float pcs = 0.f;
    #pragma unroll
    for (int i = 0; i < 2; i++)
      #pragma unroll
      for (int r = 0; r < 4; r++) pcs += tmv[i][r] ? ev[i][j][r] : 0.f;
    pcs += __shfl_xor(pcs, 16);
    pcs += __shfl_xor(pcs, 32);
    if (q == 0) {
      int gcol = b0 + wc * 64 + j * 16 + c;
      atomicAdd(&colsum[b * M_ + gcol], pcs);
    }
  }
  __syncthreads();
  u16* et = (u16*)smem;
  #pragma unroll
  for (int i = 0; i < 2; i++)
    #pragma unroll
    for (int j = 0; j < 4; j++) {
      int gcolL = wc * 64 + j * 16 + c;
      int arL = wr * 32 + i * 16 + q * 4;
      u32 lo = (u32)f2bf(ev[i][j][0]) | ((u32)f2bf(ev[i][j][1]) << 16);
      u32 hi = (u32)f2bf(ev[i][j][2]) | ((u32)f2bf(ev[i][j][3]) << 16);
      uint2 pk; pk.x = lo; pk.y = hi;
      *(uint2*)&et[gcolL * 72 + arL] = pk;
    }
  __syncthreads();
  #pragma unroll
  for (int it = 0; it < 4; it++) {
    int mrow = (tid >> 3) + it * 32;
    int l8 = tid & 7;
    uint4 v = *(const uint4*)&et[mrow * 72 + l8 * 8];
    *(uint4*)&ET[((size_t)(b * M_ + b0 + mrow)) * L_ + a0 + l8 * 8] = v;
  }
}

// ---------------------------------------------------------------------------
// gemm_ct: c_f32[h][m] += sum_l textT_m[h][l] * ET[m][l]  (split-K x2, f32
// atomics). 512 threads, 8 waves (2x4), tile 64x128. 1D grid 512, XCD swizzle.
// ---------------------------------------------------------------------------
__global__ __launch_bounds__(512) void gemm_ct(
    const u16* __restrict__ A, const u16* __restrict__ ET,
    float* __restrict__ c_f32)
{
  int f = blockIdx.x;                      // 512 = 8 * 64
  int orig = (f & 7) * 64 + (f >> 3);      // each XCD: 2 batches
  int b = orig >> 5;
  int x = orig & 3, y = (orig >> 2) & 7;
  int ia = x & 1, ks = x >> 1;
  int a0 = ia * 64, b0 = y * 128;
  int tid = threadIdx.x, lane = tid & 63, wid = tid >> 6;
  int wr = wid >> 2, wc = wid & 3;
  int c = lane & 15, q = lane >> 4;
  __shared__ __align__(16) char smem[24576];
  const u16* Ab = A + (size_t)(b * H_ + a0) * L_;
  const u16* Bb = ET + (size_t)(b * M_ + b0) * L_;
  f32x4 acc[2][2];
  #pragma unroll
  for (int i = 0; i < 2; i++)
    #pragma unroll
    for (int j = 0; j < 2; j++) acc[i][j] = (f32x4){0.f, 0.f, 0.f, 0.f};
  for (int kt = ks * 8; kt < ks * 8 + 8; kt++) {
    __syncthreads();
    {
      int row = tid >> 3, col8 = tid & 7;
      uint4 v = *(const uint4*)(Ab + (size_t)row * L_ + kt * 64 + col8 * 8);
      *(uint4*)(smem + row * 128 + ((col8 * 16) ^ ((row & 7) << 4))) = v;
    }
    #pragma unroll
    for (int i = 0; i < 2; i++) {
      int cc = tid + 512 * i;
      int row = cc >> 3, col8 = cc & 7;
      uint4 v = *(const uint4*)(Bb + (size_t)row * L_ + kt * 64 + col8 * 8);
      *(uint4*)(smem + 8192 + row * 128 + ((col8 * 16) ^ ((row & 7) << 4))) = v;
    }
    __syncthreads();
    #pragma unroll
    for (int kk = 0; kk < 2; kk++) {
      int kbyte = kk * 64 + (q << 4);
      bf16x8 af[2], bfr[2];
      #pragma unroll
      for (int i = 0; i < 2; i++) {
        int ra = wr * 32 + i * 16 + c;
        af[i] = *(const bf16x8*)(smem + ra * 128 + (kbyte ^ ((ra & 7) << 4)));
      }
      #pragma unroll
      for (int j = 0; j < 2; j++) {
        int rb = wc * 32 + j * 16 + c;
        bfr[j] = *(const bf16x8*)(smem + 8192 + rb * 128 + (kbyte ^ ((rb & 7) << 4)));
      }
      #pragma unroll
      for (int i = 0; i < 2; i++)
        #pragma unroll
        for (int j = 0; j < 2; j++)
          acc[i][j] = __builtin_amdgcn_mfma_f32_16x16x32_bf16(af[i], bfr[j], acc[i][j], 0, 0, 0);
    }
  }
  #pragma unroll
  for (int i = 0; i < 2; i++)
    #pragma unroll
    for (int j = 0; j < 2; j++) {
      int arow0 = a0 + wr * 32 + i * 16 + q * 4;
      int gcol = b0 + wc * 32 + j * 16 + c;
      #pragma unroll
      for (int r = 0; r < 4; r++)
        atomicAdd(&c_f32[((size_t)(b * H_ + arow0 + r)) * M_ + gcol], acc[i][j][r]);
    }
}

// ---------------------------------------------------------------------------
// gemm_ab: a = (E @ mod_mT^T)/rowsum, bb = (E @ cT^T)/rowsum, K = M.
// 2-phase reg-staged pipeline (load t+1 into regs during compute of t),
// 1024 threads / 16 waves (2x8), tile 64(l) x 128(h). B2 staged from c_f32
// scaled by invcm = mmask/colsum. Writes out[text | a | text*a | text*bb].
// 1D grid 256, XCD swizzle.
// ---------------------------------------------------------------------------
__global__ __launch_bounds__(1024) void gemm_ab(
    const u16* __restrict__ ET, const u16* __restrict__ B1,
    const float* __restrict__ c_f32, const float* __restrict__ colsum,
    const int* __restrict__ mmask, const float* __restrict__ rowsum,
    const float* __restrict__ text, float* __restrict__ out)
{
  int f = blockIdx.x;                      // 256 = 8 * 32
  int orig = (f & 7) * 32 + (f >> 3);      // each XCD: 2 batches
  int b = orig >> 4;
  int a0 = (orig & 15) * 64;
  int tid = threadIdx.x, lane = tid & 63, wid = tid >> 6;   // wid 0..15
  int wr = wid >> 3, wc = wid & 7;
  int c = lane & 15, q = lane >> 4;
  __shared__ __align__(16) u16 At[64 * 76];       // [m 64][l 64] pad 76
  __shared__ __align__(16) char Bs[2][16384];
  __shared__ float invcm[1024];
  const u16* ETb = ET + (size_t)b * M_ * L_;
  const u16* B1b = B1 + (size_t)b * H_ * M_;
  const float* cfb = c_f32 + (size_t)b * H_ * M_;
  invcm[tid] = mmask[b * M_ + tid] ? 1.0f / fmaxf(colsum[b * M_ + tid], 1e-30f) : 0.f;

  // staging coords (per thread, fixed)
  int sArow = tid >> 4, sAcol = (tid & 15) * 4;   // A: 64 x 64 u16, uint2 each
  int sBrow = tid >> 3, sBcol8 = tid & 7;         // B: 128 x 64, uint4 each

  f32x4 acc_a[2], acc_b[2];
  #pragma unroll
  for (int i = 0; i < 2; i++) {
    acc_a[i] = (f32x4){0.f, 0.f, 0.f, 0.f};
    acc_b[i] = (f32x4){0.f, 0.f, 0.f, 0.f};
  }

  uint2 rA;
  uint4 rB1;
  float4 rB2a, rB2b;
  auto LOAD = [&](int kt) {
    rA = *(const uint2*)&ETb[((size_t)(kt * 64 + sArow)) * L_ + a0 + sAcol];
    int mbase = kt * 64 + sBcol8 * 8;
    rB1 = *(const uint4*)(B1b + (size_t)sBrow * M_ + mbase);
    rB2a = *(const float4*)&cfb[(size_t)sBrow * M_ + mbase];
    rB2b = *(const float4*)&cfb[(size_t)sBrow * M_ + mbase + 4];
  };
  auto WRITE = [&](int kt) {
    *(uint2*)(At + sArow * 76 + sAcol) = rA;
    int swz = (sBcol8 * 16) ^ ((sBrow & 7) << 4);
    *(uint4*)(Bs[0] + sBrow * 128 + swz) = rB1;
    int mbase = kt * 64 + sBcol8 * 8;
    float4 ia4 = *(const float4*)&invcm[mbase];
    float4 ib4 = *(const float4*)&invcm[mbase + 4];
    uint4 v2;
    v2.x = (u32)f2bf(rB2a.x * ia4.x) | ((u32)f2bf(rB2a.y * ia4.y) << 16);
    v2.y = (u32)f2bf(rB2a.z * ia4.z) | ((u32)f2bf(rB2a.w * ia4.w) << 16);
    v2.z = (u32)f2bf(rB2b.x * ib4.x) | ((u32)f2bf(rB2b.y * ib4.y) << 16);
    v2.w = (u32)f2bf(rB2b.z * ib4.z) | ((u32)f2bf(rB2b.w * ib4.w) << 16);
    *(uint4*)(Bs[1] + sBrow * 128 + swz) = v2;
  };

  LOAD(0);
  __syncthreads();            // invcm ready
  WRITE(0);
  for (int kt = 0; kt < 16; kt++) {
    if (kt < 15) LOAD(kt + 1);
    __syncthreads();          // staged tile kt visible
    #pragma unroll
    for (int kk = 0; kk < 2; kk++) {
      int kbyte = kk * 64 + (q << 4);
      bf16x8 af[2], b1f, b2f;
      #pragma unroll
      for (int i = 0; i < 2; i++) {
        int lidx = wr * 32 + i * 16 + c;
        int mbase = kk * 32 + q * 8;
        union { unsigned short s[8]; bf16x8 v; } ua;
        #pragma unroll
        for (int e = 0; e < 8; e++) ua.s[e] = At[(mbase + e) * 76 + lidx];
        af[i] = ua.v;
      }
      int rb = wc * 16 + c;
      b1f = *(const bf16x8*)(Bs[0] + rb * 128 + (kbyte ^ ((rb & 7) << 4)));
      b2f = *(const bf16x8*)(Bs[1] + rb * 128 + (kbyte ^ ((rb & 7) << 4)));
      #pragma unroll
      for (int i = 0; i < 2; i++) {
        acc_a[i] = __builtin_amdgcn_mfma_f32_16x16x32_bf16(af[i], b1f, acc_a[i], 0, 0, 0);
        acc_b[i] = __builtin_amdgcn_mfma_f32_16x16x32_bf16(af[i], b2f, acc_b[i], 0, 0, 0);
      }
    }
    __syncthreads();          // all reads of tile kt done
    if (kt < 15) WRITE(kt + 1);
  }

  float irs[2][4];
  #pragma unroll
  for (int i = 0; i < 2; i++)
    #pragma unroll
    for (int r = 0; r < 4; r++) {
      int ar = a0 + wr * 32 + i * 16 + q * 4 + r;
      irs[i][r] = 1.0f / fmaxf(rowsum[b * L_ + ar], 1e-30f);
    }
  int gcol = wc * 16 + c;
  #pragma unroll
  for (int i = 0; i < 2; i++) {
    #pragma unroll
    for (int r = 0; r < 4; r++) {
      int ar = a0 + wr * 32 + i * 16 + q * 4 + r;
      float av = acc_a[i][r] * irs[i][r];
      float bv = acc_b[i][r] * irs[i][r];
      float tv = text[((size_t)(b * L_ + ar)) * H_ + gcol];
      size_t base = ((size_t)(b * L_ + ar)) * 512 + gcol;
      out[base] = tv;
      out[base + 128] = av;
      out[base + 256] = tv * av;
      out[base + 384] = tv * bv;
    }
  }
}

// ---------------------------------------------------------------------------
extern "C" void kernel_launch(void* const* d_in, const int* in_sizes, int n_in,
                              void* d_out, int out_size, void* d_ws, size_t ws_size,
                              hipStream_t stream) {
  const float* text = (const float*)d_in[0];
  const float* modality = (const float*)d_in[1];
  const int* text_mask = (const int*)d_in[2];
  const int* modality_mask = (const int*)d_in[3];
  const float* text_weight = (const float*)d_in[4];
  const float* modality_weight = (const float*)d_in[5];
  const float* tmw = (const float*)d_in[6];
  const float* bias = (const float*)d_in[7];
  float* out = (float*)d_out;
  (void)in_sizes; (void)n_in; (void)out_size; (void)ws_size;

  char* ws = (char*)d_ws;
  size_t off = 0;
  auto alloc = [&](size_t bytes) { void* p = ws + off; off += (bytes + 255) & ~(size_t)255; return p; };
  u16*   ET       = (u16*)  alloc((size_t)B_ * M_ * L_ * 2);   // 33.5MB
  u16*   textw_bf = (u16*)  alloc((size_t)B_ * L_ * H_ * 2);
  u16*   mod_bf   = (u16*)  alloc((size_t)B_ * M_ * H_ * 2);
  u16*   textT_bf = (u16*)  alloc((size_t)B_ * H_ * L_ * 2);   // masked by tmask
  u16*   mod_bfT  = (u16*)  alloc((size_t)B_ * H_ * M_ * 2);   // masked by mmask
  float* t0       = (float*)alloc((size_t)B_ * L_ * 4);
  float* s1m      = (float*)alloc((size_t)B_ * M_ * 4);
  // contiguous zero region: rowsum | colsum | c_f32
  float* rowsum   = (float*)alloc((size_t)B_ * L_ * 4);
  float* colsum   = (float*)alloc((size_t)B_ * M_ * 4);
  float* c_f32    = (float*)alloc((size_t)B_ * H_ * M_ * 4);   // 8.4MB

  int n4 = (B_ * (L_ + M_) + B_ * H_ * M_) / 4;
  zero_f32<<<2048, 256, 0, stream>>>((float4*)rowsum, n4);
  prep2<<<512, 256, 0, stream>>>(text, modality, text_mask, modality_mask,
      text_weight, modality_weight, tmw,
      textw_bf, mod_bf, textT_bf, mod_bfT, t0, s1m);
  gemm_exp<<<2048, 256, 0, stream>>>(textw_bf, mod_bf, t0, s1m, bias,
      text_mask, modality_mask, rowsum, colsum, ET);
  gemm_ct<<<512, 512, 0, stream>>>(textT_bf, ET, c_f32);
  gemm_ab<<<256, 1024, 0, stream>>>(ET, mod_bfT, c_f32, colsum, modality_mask,
      rowsum, text, out);
}

// Round 7
// 160.186 us; speedup vs baseline: 1.1311x; 1.0364x over previous
//
#include <hip/hip_runtime.h>

#define B_ 16
#define L_ 1024
#define M_ 1024
#define H_ 128

typedef unsigned short u16;
typedef unsigned int u32;
typedef __bf16 bf16x8 __attribute__((ext_vector_type(8)));
typedef float f32x4 __attribute__((ext_vector_type(4)));

__device__ __forceinline__ u16 f2bf(float x){
  u32 u = __float_as_uint(x);
  u = (u + 0x7fffu + ((u >> 16) & 1u)) >> 16;
  return (u16)u;
}

__device__ __forceinline__ void gload16(const u16* g, char* l) {
  __builtin_amdgcn_global_load_lds(
      (const __attribute__((address_space(1))) u32*)(const void*)g,
      (__attribute__((address_space(3))) u32*)(void*)l, 16, 0, 0);
}

// ---------------------------------------------------------------------------
// prep2: zero accumulators + one pass over text/modality f32. Per 64-row
// chunk: row-major bf16 (text scaled by tmw), mask-zeroed transposed bf16,
// f32 dot with text_weight/modality_weight.
// grid 512 = sel(2) x b(16) x chunk(16), 256 threads.
// ---------------------------------------------------------------------------
__global__ __launch_bounds__(256) void prep2(
    const float* __restrict__ text, const float* __restrict__ modality,
    const int* __restrict__ tmask, const int* __restrict__ mmask,
    const float* __restrict__ tw, const float* __restrict__ mw,
    const float* __restrict__ tmw,
    u16* __restrict__ textw_bf, u16* __restrict__ mod_bf,
    u16* __restrict__ textT_bf, u16* __restrict__ modT_bf,
    float* __restrict__ t0, float* __restrict__ s1m,
    float4* __restrict__ zbase, int n4)
{
  // zero rowsum|colsum|c_f32 (ws poisoned 0xAA pre-launch)
  for (int i = blockIdx.x * 256 + threadIdx.x; i < n4; i += 512 * 256)
    zbase[i] = make_float4(0.f, 0.f, 0.f, 0.f);

  int g = blockIdx.x;
  int sel = g >> 8;
  int b = (g >> 4) & 15;
  int r0 = (g & 15) * 64;
  const float* src = (sel ? modality : text) + ((size_t)b * 1024 + r0) * H_;
  const int* msk = (sel ? mmask : tmask) + b * 1024 + r0;
  const float* dotw = sel ? mw : tw;
  u16* rowout = (sel ? mod_bf : textw_bf) + ((size_t)b * 1024 + r0) * H_;
  u16* trout = (sel ? modT_bf : textT_bf) + (size_t)b * H_ * 1024 + r0;
  float* dotout = (sel ? s1m : t0) + b * 1024 + r0;

  __shared__ u16 tile[128][72];     // [h][l], rows 144B (16-aligned)
  int tid = threadIdx.x;
  int rgrp = tid >> 5;
  int lane32 = tid & 31;
  int h0 = lane32 * 4;
  float4 w4 = *(const float4*)&dotw[h0];
  float4 mv = sel ? make_float4(1.f, 1.f, 1.f, 1.f) : *(const float4*)&tmw[h0];
  float dpart[8];
  #pragma unroll
  for (int p = 0; p < 8; p++) {
    int row = rgrp + p * 8;
    float4 x = *(const float4*)&src[(size_t)row * H_ + h0];
    dpart[p] = x.x * w4.x + x.y * w4.y + x.z * w4.z + x.w * w4.w;
    uint2 pk;
    pk.x = (u32)f2bf(x.x * mv.x) | ((u32)f2bf(x.y * mv.y) << 16);
    pk.y = (u32)f2bf(x.z * mv.z) | ((u32)f2bf(x.w * mv.w) << 16);
    *(uint2*)&rowout[(size_t)row * H_ + h0] = pk;
    int mk = msk[row];
    tile[h0 + 0][row] = mk ? f2bf(x.x) : (u16)0;
    tile[h0 + 1][row] = mk ? f2bf(x.y) : (u16)0;
    tile[h0 + 2][row] = mk ? f2bf(x.z) : (u16)0;
    tile[h0 + 3][row] = mk ? f2bf(x.w) : (u16)0;
  }
  #pragma unroll
  for (int p = 0; p < 8; p++) {
    float d = dpart[p];
    #pragma unroll
    for (int off = 1; off < 32; off <<= 1) d += __shfl_xor(d, off);
    if (lane32 == 0) dotout[rgrp + p * 8] = d;
  }
  __syncthreads();
  int lcol = (tid & 7) * 8;
  #pragma unroll
  for (int p = 0; p < 4; p++) {
    int h = (tid >> 3) + p * 32;
    uint4 v = *(const uint4*)&tile[h][lcol];
    *(uint4*)&trout[(size_t)h * 1024 + lcol] = v;
  }
}

// ---------------------------------------------------------------------------
// gemm_exp: s = textw @ mod^T + t0 + s1m + bias; E = exp(s) (no max-sub:
// |s| <~ 15). Staging via global_load_lds width=16, pre-swizzled source
// (linear LDS dest; source col permutation == read-side XOR swizzle).
// Writes E^T (M,L) bf16 via LDS repack; atomics for masked rowsum/colsum.
// Tile 64(l) x 128(m), 4 waves. 1D grid 2048, XCD swizzle.
// ---------------------------------------------------------------------------
__global__ __launch_bounds__(256) void gemm_exp(
    const u16* __restrict__ A, const u16* __restrict__ Bm,
    const float* __restrict__ t0, const float* __restrict__ s1m,
    const float* __restrict__ bias, const int* __restrict__ tmask,
    const int* __restrict__ mmask, float* __restrict__ rowsum,
    float* __restrict__ colsum, u16* __restrict__ ET)
{
  int f = blockIdx.x;                       // 2048 = 8 xcd * 256
  int orig = (f & 7) * 256 + (f >> 3);      // each XCD: 2 batches
  int b = orig >> 7;
  int a0 = (orig & 15) * 64, b0 = ((orig >> 4) & 7) * 128;
  int tid = threadIdx.x, lane = tid & 63, wid = tid >> 6;
  int wr = wid >> 1, wc = wid & 1;
  int c = lane & 15, q = lane >> 4;
  __shared__ __align__(16) char smem[24576];
  const u16* Ab = A + (size_t)(b * L_ + a0) * H_;
  const u16* Bb = Bm + (size_t)(b * M_ + b0) * H_;
  // pre-swizzled staging coords: lane ln -> row w*8+i*32+(ln>>3),
  // source col8 = (ln&7) ^ (ln>>3); LDS dest linear (wave-uniform base).
  int rsub = lane >> 3;
  int scol8 = (lane & 7) ^ rsub;
  f32x4 acc[2][4];
  #pragma unroll
  for (int i = 0; i < 2; i++)
    #pragma unroll
    for (int j = 0; j < 4; j++) acc[i][j] = (f32x4){0.f, 0.f, 0.f, 0.f};
  for (int kt = 0; kt < 2; kt++) {
    __syncthreads();
    #pragma unroll
    for (int i = 0; i < 2; i++)       // A: 64x64
      gload16(Ab + (size_t)(wid * 8 + i * 32 + rsub) * H_ + kt * 64 + scol8 * 8,
              smem + wid * 1024 + i * 4096);
    #pragma unroll
    for (int i = 0; i < 4; i++)       // B: 128x64
      gload16(Bb + (size_t)(wid * 8 + i * 32 + rsub) * H_ + kt * 64 + scol8 * 8,
              smem + 8192 + wid * 1024 + i * 4096);
    __syncthreads();
    #pragma unroll
    for (int kk = 0; kk < 2; kk++) {
      int kbyte = kk * 64 + (q << 4);
      bf16x8 af[2], bfr[4];
      #pragma unroll
      for (int i = 0; i < 2; i++) {
        int ra = wr * 32 + i * 16 + c;
        af[i] = *(const bf16x8*)(smem + ra * 128 + (kbyte ^ ((ra & 7) << 4)));
      }
      #pragma unroll
      for (int j = 0; j < 4; j++) {
        int rb = wc * 64 + j * 16 + c;
        bfr[j] = *(const bf16x8*)(smem + 8192 + rb * 128 + (kbyte ^ ((rb & 7) << 4)));
      }
      #pragma unroll
      for (int i = 0; i < 2; i++)
        #pragma unroll
        for (int j = 0; j < 4; j++)
          acc[i][j] = __builtin_amdgcn_mfma_f32_16x16x32_bf16(af[i], bfr[j], acc[i][j], 0, 0, 0);
    }
  }
  float biasv = bias[0];
  float t0v[2][4];
  int tmv[2][4];
  #pragma unroll
  for (int i = 0; i < 2; i++)
    #pragma unroll
    for (int r = 0; r < 4; r++) {
      int ar = a0 + wr * 32 + i * 16 + q * 4 + r;
      t0v[i][r] = t0[b * L_ + ar];
      tmv[i][r] = tmask[b * L_ + ar];
    }
  float s1v[4];
  int mmv[4];
  #pragma unroll
  for (int j = 0; j < 4; j++) {
    int gcol = b0 + wc * 64 + j * 16 + c;
    s1v[j] = s1m[b * M_ + gcol];
    mmv[j] = mmask[b * M_ + gcol];
  }
  float ev[2][4][4];
  #pragma unroll
  for (int i = 0; i < 2; i++)
    #pragma unroll
    for (int j = 0; j < 4; j++)
      #pragma unroll
      for (int r = 0; r < 4; r++)
        ev[i][j][r] = __expf(acc[i][j][r] + t0v[i][r] + s1v[j] + biasv);
  #pragma unroll
  for (int i = 0; i < 2; i++)
    #pragma unroll
    for (int r = 0; r < 4; r++) {
      float prs = 0.f;
      #pragma unroll
      for (int j = 0; j < 4; j++) prs += mmv[j] ? ev[i][j][r] : 0.f;
      #pragma unroll
      for (int off = 1; off < 16; off <<= 1) prs += __shfl_xor(prs, off);
      if (c == 0) {
        int ar = a0 + wr * 32 + i * 16 + q * 4 + r;
        atomicAdd(&rowsum[b * L_ + ar], prs);
      }
    }
  #pragma unroll
  for (int j = 0; j < 4; j++) {
    float pcs = 0.f;
    #pragma unroll
    for (int i = 0; i < 2; i++)
      #pragma unroll
      for (int r = 0; r < 4; r++) pcs += tmv[i][r] ? ev[i][j][r] : 0.f;
    pcs += __shfl_xor(pcs, 16);
    pcs += __shfl_xor(pcs, 32);
    if (q == 0) {
      int gcol = b0 + wc * 64 + j * 16 + c;
      atomicAdd(&colsum[b * M_ + gcol], pcs);
    }
  }
  __syncthreads();
  u16* et = (u16*)smem;
  #pragma unroll
  for (int i = 0; i < 2; i++)
    #pragma unroll
    for (int j = 0; j < 4; j++) {
      int gcolL = wc * 64 + j * 16 + c;
      int arL = wr * 32 + i * 16 + q * 4;
      u32 lo = (u32)f2bf(ev[i][j][0]) | ((u32)f2bf(ev[i][j][1]) << 16);
      u32 hi = (u32)f2bf(ev[i][j][2]) | ((u32)f2bf(ev[i][j][3]) << 16);
      uint2 pk; pk.x = lo; pk.y = hi;
      *(uint2*)&et[gcolL * 72 + arL] = pk;
    }
  __syncthreads();
  #pragma unroll
  for (int it = 0; it < 4; it++) {
    int mrow = (tid >> 3) + it * 32;
    int l8 = tid & 7;
    uint4 v = *(const uint4*)&et[mrow * 72 + l8 * 8];
    *(uint4*)&ET[((size_t)(b * M_ + b0 + mrow)) * L_ + a0 + l8 * 8] = v;
  }
}

// ---------------------------------------------------------------------------
// gemm_ct: c_f32[h][m] += sum_l textT_m[h][l] * ET[m][l]  (split-K x2, f32
// atomics). 2-phase reg-staged pipeline. 512 threads, 8 waves (2x4),
// tile 64x128. 1D grid 512, XCD swizzle.
// ---------------------------------------------------------------------------
__global__ __launch_bounds__(512) void gemm_ct(
    const u16* __restrict__ A, const u16* __restrict__ ET,
    float* __restrict__ c_f32)
{
  int f = blockIdx.x;                      // 512 = 8 * 64
  int orig = (f & 7) * 64 + (f >> 3);      // each XCD: 2 batches
  int b = orig >> 5;
  int x = orig & 3, y = (orig >> 2) & 7;
  int ia = x & 1, ks = x >> 1;
  int a0 = ia * 64, b0 = y * 128;
  int tid = threadIdx.x, lane = tid & 63, wid = tid >> 6;
  int wr = wid >> 2, wc = wid & 3;
  int c = lane & 15, q = lane >> 4;
  __shared__ __align__(16) char smem[24576];
  const u16* Ab = A + (size_t)(b * H_ + a0) * L_;
  const u16* Bb = ET + (size_t)(b * M_ + b0) * L_;
  // staging coords: A 64x64 u16 = 512 uint4 (1/thread); B 128x64 (2/thread)
  int sRow = tid >> 3, sCol8 = tid & 7;
  int swzA = sRow * 128 + ((sCol8 * 16) ^ ((sRow & 7) << 4));
  f32x4 acc[2][2];
  #pragma unroll
  for (int i = 0; i < 2; i++)
    #pragma unroll
    for (int j = 0; j < 2; j++) acc[i][j] = (f32x4){0.f, 0.f, 0.f, 0.f};

  uint4 rA, rB0, rB1;
  auto LOAD = [&](int kt) {
    rA = *(const uint4*)(Ab + (size_t)sRow * L_ + kt * 64 + sCol8 * 8);
    rB0 = *(const uint4*)(Bb + (size_t)sRow * L_ + kt * 64 + sCol8 * 8);
    rB1 = *(const uint4*)(Bb + (size_t)(sRow + 64) * L_ + kt * 64 + sCol8 * 8);
  };
  auto WRITE = [&]() {
    *(uint4*)(smem + swzA) = rA;
    *(uint4*)(smem + 8192 + swzA) = rB0;
    *(uint4*)(smem + 8192 + 8192 + swzA) = rB1;   // rows 64..127 share row&7
  };
  int kt0 = ks * 8;
  LOAD(kt0);
  WRITE();
  for (int t = 0; t < 8; t++) {
    if (t < 7) LOAD(kt0 + t + 1);
    __syncthreads();
    #pragma unroll
    for (int kk = 0; kk < 2; kk++) {
      int kbyte = kk * 64 + (q << 4);
      bf16x8 af[2], bfr[2];
      #pragma unroll
      for (int i = 0; i < 2; i++) {
        int ra = wr * 32 + i * 16 + c;
        af[i] = *(const bf16x8*)(smem + ra * 128 + (kbyte ^ ((ra & 7) << 4)));
      }
      #pragma unroll
      for (int j = 0; j < 2; j++) {
        int rb = wc * 32 + j * 16 + c;
        bfr[j] = *(const bf16x8*)(smem + 8192 + rb * 128 + (kbyte ^ ((rb & 7) << 4)));
      }
      #pragma unroll
      for (int i = 0; i < 2; i++)
        #pragma unroll
        for (int j = 0; j < 2; j++)
          acc[i][j] = __builtin_amdgcn_mfma_f32_16x16x32_bf16(af[i], bfr[j], acc[i][j], 0, 0, 0);
    }
    __syncthreads();
    if (t < 7) WRITE();
  }
  #pragma unroll
  for (int i = 0; i < 2; i++)
    #pragma unroll
    for (int j = 0; j < 2; j++) {
      int arow0 = a0 + wr * 32 + i * 16 + q * 4;
      int gcol = b0 + wc * 32 + j * 16 + c;
      #pragma unroll
      for (int r = 0; r < 4; r++)
        atomicAdd(&c_f32[((size_t)(b * H_ + arow0 + r)) * M_ + gcol], acc[i][j][r]);
    }
}

// ---------------------------------------------------------------------------
// gemm_ab: a = (E @ mod_mT^T)/rowsum, bb = (E @ cT^T)/rowsum, K = M.
// 2-phase reg-staged pipeline, 1024 threads / 16 waves (2x8), tile 64 x 128.
// B2 staged from c_f32 scaled by invcm = mmask/colsum.
// Writes out[text | a | text*a | text*bb]. 1D grid 256, XCD swizzle.
// ---------------------------------------------------------------------------
__global__ __launch_bounds__(1024) void gemm_ab(
    const u16* __restrict__ ET, const u16* __restrict__ B1,
    const float* __restrict__ c_f32, const float* __restrict__ colsum,
    const int* __restrict__ mmask, const float* __restrict__ rowsum,
    const float* __restrict__ text, float* __restrict__ out)
{
  int f = blockIdx.x;                      // 256 = 8 * 32
  int orig = (f & 7) * 32 + (f >> 3);      // each XCD: 2 batches
  int b = orig >> 4;
  int a0 = (orig & 15) * 64;
  int tid = threadIdx.x, lane = tid & 63, wid = tid >> 6;   // wid 0..15
  int wr = wid >> 3, wc = wid & 7;
  int c = lane & 15, q = lane >> 4;
  __shared__ __align__(16) u16 At[64 * 76];       // [m 64][l 64] pad 76
  __shared__ __align__(16) char Bs[2][16384];
  __shared__ float invcm[1024];
  const u16* ETb = ET + (size_t)b * M_ * L_;
  const u16* B1b = B1 + (size_t)b * H_ * M_;
  const float* cfb = c_f32 + (size_t)b * H_ * M_;
  invcm[tid] = mmask[b * M_ + tid] ? 1.0f / fmaxf(colsum[b * M_ + tid], 1e-30f) : 0.f;

  int sArow = tid >> 4, sAcol = (tid & 15) * 4;
  int sBrow = tid >> 3, sBcol8 = tid & 7;

  f32x4 acc_a[2], acc_b[2];
  #pragma unroll
  for (int i = 0; i < 2; i++) {
    acc_a[i] = (f32x4){0.f, 0.f, 0.f, 0.f};
    acc_b[i] = (f32x4){0.f, 0.f, 0.f, 0.f};
  }

  uint2 rA;
  uint4 rB1;
  float4 rB2a, rB2b;
  auto LOAD = [&](int kt) {
    rA = *(const uint2*)&ETb[((size_t)(kt * 64 + sArow)) * L_ + a0 + sAcol];
    int mbase = kt * 64 + sBcol8 * 8;
    rB1 = *(const uint4*)(B1b + (size_t)sBrow * M_ + mbase);
    rB2a = *(const float4*)&cfb[(size_t)sBrow * M_ + mbase];
    rB2b = *(const float4*)&cfb[(size_t)sBrow * M_ + mbase + 4];
  };
  auto WRITE = [&](int kt) {
    *(uint2*)(At + sArow * 76 + sAcol) = rA;
    int swz = (sBcol8 * 16) ^ ((sBrow & 7) << 4);
    *(uint4*)(Bs[0] + sBrow * 128 + swz) = rB1;
    int mbase = kt * 64 + sBcol8 * 8;
    float4 ia4 = *(const float4*)&invcm[mbase];
    float4 ib4 = *(const float4*)&invcm[mbase + 4];
    uint4 v2;
    v2.x = (u32)f2bf(rB2a.x * ia4.x) | ((u32)f2bf(rB2a.y * ia4.y) << 16);
    v2.y = (u32)f2bf(rB2a.z * ia4.z) | ((u32)f2bf(rB2a.w * ia4.w) << 16);
    v2.z = (u32)f2bf(rB2b.x * ib4.x) | ((u32)f2bf(rB2b.y * ib4.y) << 16);
    v2.w = (u32)f2bf(rB2b.z * ib4.z) | ((u32)f2bf(rB2b.w * ib4.w) << 16);
    *(uint4*)(Bs[1] + sBrow * 128 + swz) = v2;
  };

  LOAD(0);
  __syncthreads();            // invcm ready
  WRITE(0);
  for (int kt = 0; kt < 16; kt++) {
    if (kt < 15) LOAD(kt + 1);
    __syncthreads();          // staged tile kt visible
    #pragma unroll
    for (int kk = 0; kk < 2; kk++) {
      int kbyte = kk * 64 + (q << 4);
      bf16x8 af[2], b1f, b2f;
      #pragma unroll
      for (int i = 0; i < 2; i++) {
        int lidx = wr * 32 + i * 16 + c;
        int mbase = kk * 32 + q * 8;
        union { unsigned short s[8]; bf16x8 v; } ua;
        #pragma unroll
        for (int e = 0; e < 8; e++) ua.s[e] = At[(mbase + e) * 76 + lidx];
        af[i] = ua.v;
      }
      int rb = wc * 16 + c;
      b1f = *(const bf16x8*)(Bs[0] + rb * 128 + (kbyte ^ ((rb & 7) << 4)));
      b2f = *(const bf16x8*)(Bs[1] + rb * 128 + (kbyte ^ ((rb & 7) << 4)));
      #pragma unroll
      for (int i = 0; i < 2; i++) {
        acc_a[i] = __builtin_amdgcn_mfma_f32_16x16x32_bf16(af[i], b1f, acc_a[i], 0, 0, 0);
        acc_b[i] = __builtin_amdgcn_mfma_f32_16x16x32_bf16(af[i], b2f, acc_b[i], 0, 0, 0);
      }
    }
    __syncthreads();          // all reads of tile kt done
    if (kt < 15) WRITE(kt + 1);
  }

  float irs[2][4];
  #pragma unroll
  for (int i = 0; i < 2; i++)
    #pragma unroll
    for (int r = 0; r < 4; r++) {
      int ar = a0 + wr * 32 + i * 16 + q * 4 + r;
      irs[i][r] = 1.0f / fmaxf(rowsum[b * L_ + ar], 1e-30f);
    }
  int gcol = wc * 16 + c;
  #pragma unroll
  for (int i = 0; i < 2; i++) {
    #pragma unroll
    for (int r = 0; r < 4; r++) {
      int ar = a0 + wr * 32 + i * 16 + q * 4 + r;
      float av = acc_a[i][r] * irs[i][r];
      float bv = acc_b[i][r] * irs[i][r];
      float tv = text[((size_t)(b * L_ + ar)) * H_ + gcol];
      size_t base = ((size_t)(b * L_ + ar)) * 512 + gcol;
      out[base] = tv;
      out[base + 128] = av;
      out[base + 256] = tv * av;
      out[base + 384] = tv * bv;
    }
  }
}

// ---------------------------------------------------------------------------
extern "C" void kernel_launch(void* const* d_in, const int* in_sizes, int n_in,
                              void* d_out, int out_size, void* d_ws, size_t ws_size,
                              hipStream_t stream) {
  const float* text = (const float*)d_in[0];
  const float* modality = (const float*)d_in[1];
  const int* text_mask = (const int*)d_in[2];
  const int* modality_mask = (const int*)d_in[3];
  const float* text_weight = (const float*)d_in[4];
  const float* modality_weight = (const float*)d_in[5];
  const float* tmw = (const float*)d_in[6];
  const float* bias = (const float*)d_in[7];
  float* out = (float*)d_out;
  (void)in_sizes; (void)n_in; (void)out_size; (void)ws_size;

  char* ws = (char*)d_ws;
  size_t off = 0;
  auto alloc = [&](size_t bytes) { void* p = ws + off; off += (bytes + 255) & ~(size_t)255; return p; };
  u16*   ET       = (u16*)  alloc((size_t)B_ * M_ * L_ * 2);   // 33.5MB
  u16*   textw_bf = (u16*)  alloc((size_t)B_ * L_ * H_ * 2);
  u16*   mod_bf   = (u16*)  alloc((size_t)B_ * M_ * H_ * 2);
  u16*   textT_bf = (u16*)  alloc((size_t)B_ * H_ * L_ * 2);   // masked by tmask
  u16*   mod_bfT  = (u16*)  alloc((size_t)B_ * H_ * M_ * 2);   // masked by mmask
  float* t0       = (float*)alloc((size_t)B_ * L_ * 4);
  float* s1m      = (float*)alloc((size_t)B_ * M_ * 4);
  // contiguous zero region: rowsum | colsum | c_f32
  float* rowsum   = (float*)alloc((size_t)B_ * L_ * 4);
  float* colsum   = (float*)alloc((size_t)B_ * M_ * 4);
  float* c_f32    = (float*)alloc((size_t)B_ * H_ * M_ * 4);   // 8.4MB

  int n4 = (B_ * (L_ + M_) + B_ * H_ * M_) / 4;
  prep2<<<512, 256, 0, stream>>>(text, modality, text_mask, modality_mask,
      text_weight, modality_weight, tmw,
      textw_bf, mod_bf, textT_bf, mod_bfT, t0, s1m, (float4*)rowsum, n4);
  gemm_exp<<<2048, 256, 0, stream>>>(textw_bf, mod_bf, t0, s1m, bias,
      text_mask, modality_mask, rowsum, colsum, ET);
  gemm_ct<<<512, 512, 0, stream>>>(textT_bf, ET, c_f32);
  gemm_ab<<<256, 1024, 0, stream>>>(ET, mod_bfT, c_f32, colsum, modality_mask,
      rowsum, text, out);
}

// Round 9
// 145.587 us; speedup vs baseline: 1.2445x; 1.1003x over previous
//
#include <hip/hip_runtime.h>

#define B_ 16
#define L_ 1024
#define M_ 1024
#define H_ 128

typedef unsigned short u16;
typedef unsigned int u32;
typedef __bf16 bf16x8 __attribute__((ext_vector_type(8)));
typedef float f32x4 __attribute__((ext_vector_type(4)));

__device__ __forceinline__ u16 f2bf(float x){
  u32 u = __float_as_uint(x);
  u = (u + 0x7fffu + ((u >> 16) & 1u)) >> 16;
  return (u16)u;
}

__device__ __forceinline__ void gload16(const u16* g, char* l) {
  __builtin_amdgcn_global_load_lds(
      (const __attribute__((address_space(1))) u32*)(const void*)g,
      (__attribute__((address_space(3))) u32*)(void*)l, 16, 0, 0);
}

// ---------------------------------------------------------------------------
// prep2: zero rowsum|colsum + one pass over text/modality f32. Per 64-row
// chunk: row-major bf16 (text scaled by tmw), mask-zeroed transposed bf16,
// f32 dot with text_weight/modality_weight.
// grid 512 = sel(2) x b(16) x chunk(16), 256 threads.
// ---------------------------------------------------------------------------
__global__ __launch_bounds__(256) void prep2(
    const float* __restrict__ text, const float* __restrict__ modality,
    const int* __restrict__ tmask, const int* __restrict__ mmask,
    const float* __restrict__ tw, const float* __restrict__ mw,
    const float* __restrict__ tmw,
    u16* __restrict__ textw_bf, u16* __restrict__ mod_bf,
    u16* __restrict__ textT_bf, u16* __restrict__ modT_bf,
    float* __restrict__ t0, float* __restrict__ s1m,
    float4* __restrict__ zbase, int n4)
{
  // zero rowsum|colsum (ws poisoned 0xAA pre-launch)
  for (int i = blockIdx.x * 256 + threadIdx.x; i < n4; i += 512 * 256)
    zbase[i] = make_float4(0.f, 0.f, 0.f, 0.f);

  int g = blockIdx.x;
  int sel = g >> 8;
  int b = (g >> 4) & 15;
  int r0 = (g & 15) * 64;
  const float* src = (sel ? modality : text) + ((size_t)b * 1024 + r0) * H_;
  const int* msk = (sel ? mmask : tmask) + b * 1024 + r0;
  const float* dotw = sel ? mw : tw;
  u16* rowout = (sel ? mod_bf : textw_bf) + ((size_t)b * 1024 + r0) * H_;
  u16* trout = (sel ? modT_bf : textT_bf) + (size_t)b * H_ * 1024 + r0;
  float* dotout = (sel ? s1m : t0) + b * 1024 + r0;

  __shared__ u16 tile[128][72];     // [h][l], rows 144B (16-aligned)
  int tid = threadIdx.x;
  int rgrp = tid >> 5;
  int lane32 = tid & 31;
  int h0 = lane32 * 4;
  float4 w4 = *(const float4*)&dotw[h0];
  float4 mv = sel ? make_float4(1.f, 1.f, 1.f, 1.f) : *(const float4*)&tmw[h0];
  float dpart[8];
  #pragma unroll
  for (int p = 0; p < 8; p++) {
    int row = rgrp + p * 8;
    float4 x = *(const float4*)&src[(size_t)row * H_ + h0];
    dpart[p] = x.x * w4.x + x.y * w4.y + x.z * w4.z + x.w * w4.w;
    uint2 pk;
    pk.x = (u32)f2bf(x.x * mv.x) | ((u32)f2bf(x.y * mv.y) << 16);
    pk.y = (u32)f2bf(x.z * mv.z) | ((u32)f2bf(x.w * mv.w) << 16);
    *(uint2*)&rowout[(size_t)row * H_ + h0] = pk;
    int mk = msk[row];
    tile[h0 + 0][row] = mk ? f2bf(x.x) : (u16)0;
    tile[h0 + 1][row] = mk ? f2bf(x.y) : (u16)0;
    tile[h0 + 2][row] = mk ? f2bf(x.z) : (u16)0;
    tile[h0 + 3][row] = mk ? f2bf(x.w) : (u16)0;
  }
  #pragma unroll
  for (int p = 0; p < 8; p++) {
    float d = dpart[p];
    #pragma unroll
    for (int off = 1; off < 32; off <<= 1) d += __shfl_xor(d, off);
    if (lane32 == 0) dotout[rgrp + p * 8] = d;
  }
  __syncthreads();
  int lcol = (tid & 7) * 8;
  #pragma unroll
  for (int p = 0; p < 4; p++) {
    int h = (tid >> 3) + p * 32;
    uint4 v = *(const uint4*)&tile[h][lcol];
    *(uint4*)&trout[(size_t)h * 1024 + lcol] = v;
  }
}

// ---------------------------------------------------------------------------
// gemm_exp: s = textw @ mod^T + t0 + s1m + bias; E = exp(s) (no max-sub:
// |s| <~ 15). Staging via global_load_lds width=16, pre-swizzled source.
// Writes E^T (M,L) bf16 via LDS repack; atomics for masked rowsum/colsum.
// Tile 64(l) x 128(m), 4 waves. 1D grid 2048, XCD swizzle.
// ---------------------------------------------------------------------------
__global__ __launch_bounds__(256) void gemm_exp(
    const u16* __restrict__ A, const u16* __restrict__ Bm,
    const float* __restrict__ t0, const float* __restrict__ s1m,
    const float* __restrict__ bias, const int* __restrict__ tmask,
    const int* __restrict__ mmask, float* __restrict__ rowsum,
    float* __restrict__ colsum, u16* __restrict__ ET)
{
  int f = blockIdx.x;                       // 2048 = 8 xcd * 256
  int orig = (f & 7) * 256 + (f >> 3);      // each XCD: 2 batches
  int b = orig >> 7;
  int a0 = (orig & 15) * 64, b0 = ((orig >> 4) & 7) * 128;
  int tid = threadIdx.x, lane = tid & 63, wid = tid >> 6;
  int wr = wid >> 1, wc = wid & 1;
  int c = lane & 15, q = lane >> 4;
  __shared__ __align__(16) char smem[24576];
  const u16* Ab = A + (size_t)(b * L_ + a0) * H_;
  const u16* Bb = Bm + (size_t)(b * M_ + b0) * H_;
  int rsub = lane >> 3;
  int scol8 = (lane & 7) ^ rsub;
  f32x4 acc[2][4];
  #pragma unroll
  for (int i = 0; i < 2; i++)
    #pragma unroll
    for (int j = 0; j < 4; j++) acc[i][j] = (f32x4){0.f, 0.f, 0.f, 0.f};
  for (int kt = 0; kt < 2; kt++) {
    __syncthreads();
    #pragma unroll
    for (int i = 0; i < 2; i++)       // A: 64x64
      gload16(Ab + (size_t)(wid * 8 + i * 32 + rsub) * H_ + kt * 64 + scol8 * 8,
              smem + wid * 1024 + i * 4096);
    #pragma unroll
    for (int i = 0; i < 4; i++)       // B: 128x64
      gload16(Bb + (size_t)(wid * 8 + i * 32 + rsub) * H_ + kt * 64 + scol8 * 8,
              smem + 8192 + wid * 1024 + i * 4096);
    __syncthreads();
    #pragma unroll
    for (int kk = 0; kk < 2; kk++) {
      int kbyte = kk * 64 + (q << 4);
      bf16x8 af[2], bfr[4];
      #pragma unroll
      for (int i = 0; i < 2; i++) {
        int ra = wr * 32 + i * 16 + c;
        af[i] = *(const bf16x8*)(smem + ra * 128 + (kbyte ^ ((ra & 7) << 4)));
      }
      #pragma unroll
      for (int j = 0; j < 4; j++) {
        int rb = wc * 64 + j * 16 + c;
        bfr[j] = *(const bf16x8*)(smem + 8192 + rb * 128 + (kbyte ^ ((rb & 7) << 4)));
      }
      #pragma unroll
      for (int i = 0; i < 2; i++)
        #pragma unroll
        for (int j = 0; j < 4; j++)
          acc[i][j] = __builtin_amdgcn_mfma_f32_16x16x32_bf16(af[i], bfr[j], acc[i][j], 0, 0, 0);
    }
  }
  float biasv = bias[0];
  float t0v[2][4];
  int tmv[2][4];
  #pragma unroll
  for (int i = 0; i < 2; i++)
    #pragma unroll
    for (int r = 0; r < 4; r++) {
      int ar = a0 + wr * 32 + i * 16 + q * 4 + r;
      t0v[i][r] = t0[b * L_ + ar];
      tmv[i][r] = tmask[b * L_ + ar];
    }
  float s1v[4];
  int mmv[4];
  #pragma unroll
  for (int j = 0; j < 4; j++) {
    int gcol = b0 + wc * 64 + j * 16 + c;
    s1v[j] = s1m[b * M_ + gcol];
    mmv[j] = mmask[b * M_ + gcol];
  }
  float ev[2][4][4];
  #pragma unroll
  for (int i = 0; i < 2; i++)
    #pragma unroll
    for (int j = 0; j < 4; j++)
      #pragma unroll
      for (int r = 0; r < 4; r++)
        ev[i][j][r] = __expf(acc[i][j][r] + t0v[i][r] + s1v[j] + biasv);
  #pragma unroll
  for (int i = 0; i < 2; i++)
    #pragma unroll
    for (int r = 0; r < 4; r++) {
      float prs = 0.f;
      #pragma unroll
      for (int j = 0; j < 4; j++) prs += mmv[j] ? ev[i][j][r] : 0.f;
      #pragma unroll
      for (int off = 1; off < 16; off <<= 1) prs += __shfl_xor(prs, off);
      if (c == 0) {
        int ar = a0 + wr * 32 + i * 16 + q * 4 + r;
        atomicAdd(&rowsum[b * L_ + ar], prs);
      }
    }
  #pragma unroll
  for (int j = 0; j < 4; j++) {
    float pcs = 0.f;
    #pragma unroll
    for (int i = 0; i < 2; i++)
      #pragma unroll
      for (int r = 0; r < 4; r++) pcs += tmv[i][r] ? ev[i][j][r] : 0.f;
    pcs += __shfl_xor(pcs, 16);
    pcs += __shfl_xor(pcs, 32);
    if (q == 0) {
      int gcol = b0 + wc * 64 + j * 16 + c;
      atomicAdd(&colsum[b * M_ + gcol], pcs);
    }
  }
  __syncthreads();
  u16* et = (u16*)smem;
  #pragma unroll
  for (int i = 0; i < 2; i++)
    #pragma unroll
    for (int j = 0; j < 4; j++) {
      int gcolL = wc * 64 + j * 16 + c;
      int arL = wr * 32 + i * 16 + q * 4;
      u32 lo = (u32)f2bf(ev[i][j][0]) | ((u32)f2bf(ev[i][j][1]) << 16);
      u32 hi = (u32)f2bf(ev[i][j][2]) | ((u32)f2bf(ev[i][j][3]) << 16);
      uint2 pk; pk.x = lo; pk.y = hi;
      *(uint2*)&et[gcolL * 72 + arL] = pk;
    }
  __syncthreads();
  #pragma unroll
  for (int it = 0; it < 4; it++) {
    int mrow = (tid >> 3) + it * 32;
    int l8 = tid & 7;
    uint4 v = *(const uint4*)&et[mrow * 72 + l8 * 8];
    *(uint4*)&ET[((size_t)(b * M_ + b0 + mrow)) * L_ + a0 + l8 * 8] = v;
  }
}

// ---------------------------------------------------------------------------
// gemm_ct: cT[h][m] = bf16( (sum_l textT_m[h][l] * ET[m][l]) * mmask/colsum )
// Full K=1024, 2-phase reg-staged pipeline, no atomics. 512 threads, 8 waves
// (2x4), tile 64(h) x 128(m). 1D grid 256, XCD swizzle.
// ---------------------------------------------------------------------------
__global__ __launch_bounds__(512) void gemm_ct(
    const u16* __restrict__ A, const u16* __restrict__ ET,
    const int* __restrict__ mmask, const float* __restrict__ colsum,
    u16* __restrict__ cT)
{
  int f = blockIdx.x;                      // 256 = 8 * 32
  int orig = (f & 7) * 32 + (f >> 3);      // each XCD: 2 batches
  int b = orig >> 4;
  int rem = orig & 15;
  int a0 = (rem & 1) * 64, b0 = (rem >> 1) * 128;
  int tid = threadIdx.x, lane = tid & 63, wid = tid >> 6;
  int wr = wid >> 2, wc = wid & 3;
  int c = lane & 15, q = lane >> 4;
  __shared__ __align__(16) char smem[24576];
  const u16* Ab = A + (size_t)(b * H_ + a0) * L_;
  const u16* Bb = ET + (size_t)(b * M_ + b0) * L_;
  int sRow = tid >> 3, sCol8 = tid & 7;
  int swzA = sRow * 128 + ((sCol8 * 16) ^ ((sRow & 7) << 4));
  f32x4 acc[2][2];
  #pragma unroll
  for (int i = 0; i < 2; i++)
    #pragma unroll
    for (int j = 0; j < 2; j++) acc[i][j] = (f32x4){0.f, 0.f, 0.f, 0.f};

  uint4 rA, rB0, rB1;
  auto LOAD = [&](int kt) {
    rA = *(const uint4*)(Ab + (size_t)sRow * L_ + kt * 64 + sCol8 * 8);
    rB0 = *(const uint4*)(Bb + (size_t)sRow * L_ + kt * 64 + sCol8 * 8);
    rB1 = *(const uint4*)(Bb + (size_t)(sRow + 64) * L_ + kt * 64 + sCol8 * 8);
  };
  auto WRITE = [&]() {
    *(uint4*)(smem + swzA) = rA;
    *(uint4*)(smem + 8192 + swzA) = rB0;
    *(uint4*)(smem + 8192 + 8192 + swzA) = rB1;   // rows 64..127 share row&7
  };
  LOAD(0);
  WRITE();
  for (int t = 0; t < 16; t++) {
    if (t < 15) LOAD(t + 1);
    __syncthreads();
    #pragma unroll
    for (int kk = 0; kk < 2; kk++) {
      int kbyte = kk * 64 + (q << 4);
      bf16x8 af[2], bfr[2];
      #pragma unroll
      for (int i = 0; i < 2; i++) {
        int ra = wr * 32 + i * 16 + c;
        af[i] = *(const bf16x8*)(smem + ra * 128 + (kbyte ^ ((ra & 7) << 4)));
      }
      #pragma unroll
      for (int j = 0; j < 2; j++) {
        int rb = wc * 32 + j * 16 + c;
        bfr[j] = *(const bf16x8*)(smem + 8192 + rb * 128 + (kbyte ^ ((rb & 7) << 4)));
      }
      #pragma unroll
      for (int i = 0; i < 2; i++)
        #pragma unroll
        for (int j = 0; j < 2; j++)
          acc[i][j] = __builtin_amdgcn_mfma_f32_16x16x32_bf16(af[i], bfr[j], acc[i][j], 0, 0, 0);
    }
    __syncthreads();
    if (t < 15) WRITE();
  }
  float invc[2];
  #pragma unroll
  for (int j = 0; j < 2; j++) {
    int gcol = b0 + wc * 32 + j * 16 + c;
    invc[j] = mmask[b * M_ + gcol] ? 1.0f / fmaxf(colsum[b * M_ + gcol], 1e-30f) : 0.f;
  }
  #pragma unroll
  for (int i = 0; i < 2; i++)
    #pragma unroll
    for (int j = 0; j < 2; j++) {
      int arow0 = a0 + wr * 32 + i * 16 + q * 4;
      int gcol = b0 + wc * 32 + j * 16 + c;
      #pragma unroll
      for (int r = 0; r < 4; r++)
        cT[((size_t)(b * H_ + arow0 + r)) * M_ + gcol] = f2bf(acc[i][j][r] * invc[j]);
    }
}

// ---------------------------------------------------------------------------
// gemm_ab: a = (E @ mod_mT^T)/rowsum, bb = (E @ cT^T)/rowsum, K = M.
// 2-phase reg-staged pipeline, 1024 threads / 16 waves (2x8), tile 64 x 128.
// Writes out[text | a | text*a | text*bb]. 1D grid 256, XCD swizzle.
// ---------------------------------------------------------------------------
__global__ __launch_bounds__(1024) void gemm_ab(
    const u16* __restrict__ ET, const u16* __restrict__ B1,
    const u16* __restrict__ B2, const float* __restrict__ rowsum,
    const float* __restrict__ text, float* __restrict__ out)
{
  int f = blockIdx.x;                      // 256 = 8 * 32
  int orig = (f & 7) * 32 + (f >> 3);      // each XCD: 2 batches
  int b = orig >> 4;
  int a0 = (orig & 15) * 64;
  int tid = threadIdx.x, lane = tid & 63, wid = tid >> 6;   // wid 0..15
  int wr = wid >> 3, wc = wid & 7;
  int c = lane & 15, q = lane >> 4;
  __shared__ __align__(16) u16 At[64 * 76];       // [m 64][l 64] pad 76
  __shared__ __align__(16) char Bs[2][16384];
  const u16* ETb = ET + (size_t)b * M_ * L_;
  const u16* B1b = B1 + (size_t)b * H_ * M_;
  const u16* B2b = B2 + (size_t)b * H_ * M_;

  int sArow = tid >> 4, sAcol = (tid & 15) * 4;
  int sBrow = tid >> 3, sBcol8 = tid & 7;
  int swzB = sBrow * 128 + ((sBcol8 * 16) ^ ((sBrow & 7) << 4));

  f32x4 acc_a[2], acc_b[2];
  #pragma unroll
  for (int i = 0; i < 2; i++) {
    acc_a[i] = (f32x4){0.f, 0.f, 0.f, 0.f};
    acc_b[i] = (f32x4){0.f, 0.f, 0.f, 0.f};
  }

  uint2 rA;
  uint4 rB1, rB2;
  auto LOAD = [&](int kt) {
    rA = *(const uint2*)&ETb[((size_t)(kt * 64 + sArow)) * L_ + a0 + sAcol];
    int mbase = kt * 64 + sBcol8 * 8;
    rB1 = *(const uint4*)(B1b + (size_t)sBrow * M_ + mbase);
    rB2 = *(const uint4*)(B2b + (size_t)sBrow * M_ + mbase);
  };
  auto WRITE = [&]() {
    *(uint2*)(At + sArow * 76 + sAcol) = rA;
    *(uint4*)(Bs[0] + swzB) = rB1;
    *(uint4*)(Bs[1] + swzB) = rB2;
  };

  LOAD(0);
  WRITE();
  for (int kt = 0; kt < 16; kt++) {
    if (kt < 15) LOAD(kt + 1);
    __syncthreads();          // staged tile kt visible
    #pragma unroll
    for (int kk = 0; kk < 2; kk++) {
      int kbyte = kk * 64 + (q << 4);
      bf16x8 af[2], b1f, b2f;
      #pragma unroll
      for (int i = 0; i < 2; i++) {
        int lidx = wr * 32 + i * 16 + c;
        int mbase = kk * 32 + q * 8;
        union { unsigned short s[8]; bf16x8 v; } ua;
        #pragma unroll
        for (int e = 0; e < 8; e++) ua.s[e] = At[(mbase + e) * 76 + lidx];
        af[i] = ua.v;
      }
      int rb = wc * 16 + c;
      b1f = *(const bf16x8*)(Bs[0] + rb * 128 + (kbyte ^ ((rb & 7) << 4)));
      b2f = *(const bf16x8*)(Bs[1] + rb * 128 + (kbyte ^ ((rb & 7) << 4)));
      #pragma unroll
      for (int i = 0; i < 2; i++) {
        acc_a[i] = __builtin_amdgcn_mfma_f32_16x16x32_bf16(af[i], b1f, acc_a[i], 0, 0, 0);
        acc_b[i] = __builtin_amdgcn_mfma_f32_16x16x32_bf16(af[i], b2f, acc_b[i], 0, 0, 0);
      }
    }
    __syncthreads();          // all reads of tile kt done
    if (kt < 15) WRITE();
  }

  float irs[2][4];
  #pragma unroll
  for (int i = 0; i < 2; i++)
    #pragma unroll
    for (int r = 0; r < 4; r++) {
      int ar = a0 + wr * 32 + i * 16 + q * 4 + r;
      irs[i][r] = 1.0f / fmaxf(rowsum[b * L_ + ar], 1e-30f);
    }
  int gcol = wc * 16 + c;
  #pragma unroll
  for (int i = 0; i < 2; i++) {
    #pragma unroll
    for (int r = 0; r < 4; r++) {
      int ar = a0 + wr * 32 + i * 16 + q * 4 + r;
      float av = acc_a[i][r] * irs[i][r];
      float bv = acc_b[i][r] * irs[i][r];
      float tv = text[((size_t)(b * L_ + ar)) * H_ + gcol];
      size_t base = ((size_t)(b * L_ + ar)) * 512 + gcol;
      out[base] = tv;
      out[base + 128] = av;
      out[base + 256] = tv * av;
      out[base + 384] = tv * bv;
    }
  }
}

// ---------------------------------------------------------------------------
extern "C" void kernel_launch(void* const* d_in, const int* in_sizes, int n_in,
                              void* d_out, int out_size, void* d_ws, size_t ws_size,
                              hipStream_t stream) {
  const float* text = (const float*)d_in[0];
  const float* modality = (const float*)d_in[1];
  const int* text_mask = (const int*)d_in[2];
  const int* modality_mask = (const int*)d_in[3];
  const float* text_weight = (const float*)d_in[4];
  const float* modality_weight = (const float*)d_in[5];
  const float* tmw = (const float*)d_in[6];
  const float* bias = (const float*)d_in[7];
  float* out = (float*)d_out;
  (void)in_sizes; (void)n_in; (void)out_size; (void)ws_size;

  char* ws = (char*)d_ws;
  size_t off = 0;
  auto alloc = [&](size_t bytes) { void* p = ws + off; off += (bytes + 255) & ~(size_t)255; return p; };
  u16*   ET       = (u16*)  alloc((size_t)B_ * M_ * L_ * 2);   // 33.5MB
  u16*   textw_bf = (u16*)  alloc((size_t)B_ * L_ * H_ * 2);
  u16*   mod_bf   = (u16*)  alloc((size_t)B_ * M_ * H_ * 2);
  u16*   textT_bf = (u16*)  alloc((size_t)B_ * H_ * L_ * 2);   // masked by tmask
  u16*   mod_bfT  = (u16*)  alloc((size_t)B_ * H_ * M_ * 2);   // masked by mmask
  u16*   cT       = (u16*)  alloc((size_t)B_ * H_ * M_ * 2);
  float* t0       = (float*)alloc((size_t)B_ * L_ * 4);
  float* s1m      = (float*)alloc((size_t)B_ * M_ * 4);
  // contiguous zero region: rowsum | colsum
  float* rowsum   = (float*)alloc((size_t)B_ * L_ * 4);
  float* colsum   = (float*)alloc((size_t)B_ * M_ * 4);

  int n4 = (B_ * (L_ + M_)) / 4;
  prep2<<<512, 256, 0, stream>>>(text, modality, text_mask, modality_mask,
      text_weight, modality_weight, tmw,
      textw_bf, mod_bf, textT_bf, mod_bfT, t0, s1m, (float4*)rowsum, n4);
  gemm_exp<<<2048, 256, 0, stream>>>(textw_bf, mod_bf, t0, s1m, bias,
      text_mask, modality_mask, rowsum, colsum, ET);
  gemm_ct<<<256, 512, 0, stream>>>(textT_bf, ET, modality_mask, colsum, cT);
  gemm_ab<<<256, 1024, 0, stream>>>(ET, mod_bfT, cT, rowsum, text, out);
}